// Round 4
// baseline (269.958 us; speedup 1.0000x reference)
//
#include <hip/hip_runtime.h>
#include <math.h>

#define N 4096
#define D 128
#define P 16
#define KK 2048                    // P*D, single bf16 plane
#define NT 32
#define NBLK (NT * (NT + 1) / 2)   // 528 upper-tri blocks
#define LCAP 3072                  // per-block LDS worklist (12 KB)
#define CAP (1u << 20)             // global worklist capacity (4 MB)
#define WIN 5e-3f                  // > 3.92e-3 rigorous single-bf16 bound

typedef __attribute__((ext_vector_type(8))) __bf16 bf16x8;
typedef __attribute__((ext_vector_type(4))) float f32x4;
typedef __attribute__((ext_vector_type(8))) unsigned short ushort8;
typedef __attribute__((address_space(1))) const unsigned int* gptr_t;
typedef __attribute__((address_space(3))) unsigned int* lptr_t;

__device__ inline unsigned short f2bf(float f) {
    unsigned int u = __float_as_uint(f);
    return (unsigned short)((u + 0x7FFFu + ((u >> 16) & 1u)) >> 16);
}

// ---------------------------------------------------------------------------
// K1: fused norms (f64, cross-lane reduce) + bf16 pack + counter init.
// Block n; thread t: p = t>>4, d0 = (t&15)*8.
// ---------------------------------------------------------------------------
__global__ __launch_bounds__(256) void k_pack(const float* __restrict__ c,
                                              const float* __restrict__ w,
                                              double* __restrict__ rnorm,
                                              unsigned short* __restrict__ zb,
                                              unsigned* gcnt, unsigned* govf,
                                              int do_init) {
    int n = blockIdx.x, tid = threadIdx.x;
    if (do_init && n == 0 && tid == 0) { *gcnt = 0; *govf = 0; }
    int p = tid >> 4, d0 = (tid & 15) * 8;
    const float* cc = c + (size_t)n * D + d0;
    const float* ww = w + (size_t)p * D + d0;
    float cv[8], wv[8];
    *(float4*)&cv[0] = *(const float4*)&cc[0];
    *(float4*)&cv[4] = *(const float4*)&cc[4];
    *(float4*)&wv[0] = *(const float4*)&ww[0];
    *(float4*)&wv[4] = *(const float4*)&ww[4];
    double s = 0.0;
#pragma unroll
    for (int i = 0; i < 8; ++i) {
        double v = (double)cv[i] * (double)wv[i];
        s += v * v;
    }
#pragma unroll
    for (int o = 1; o < 16; o <<= 1) s += __shfl_xor(s, o, 64);
    double rn = 1.0 / fmax(sqrt(s), 1e-12);
    if ((tid & 15) == 0) rnorm[p * N + n] = rn;
    float rnf = (float)rn;
    ushort8 o8;
#pragma unroll
    for (int i = 0; i < 8; ++i) o8[i] = f2bf(cv[i] * wv[i] * rnf);
    *(ushort8*)&zb[(size_t)n * KK + tid * 8] = o8;
}

// ---------------------------------------------------------------------------
// K2: bf16 MFMA GEMM out = Z Z^T / 16, fused mask + boundary worklist.
// 128x128 tile, BK=32, 4 waves (2x2 of 64x64). Upper-tri blocks; mirror via
// native float4 store (fragment acc quads are consecutive mirror columns).
// LDS staging XOR-swizzled via pre-swizzled global source (rule 21).
// ---------------------------------------------------------------------------
template <bool FUSED>
__global__ __launch_bounds__(256, 4) void k_gemm(const unsigned short* __restrict__ zb,
                                                 float* __restrict__ out,
                                                 unsigned* __restrict__ gcnt,
                                                 unsigned* __restrict__ govf,
                                                 unsigned* __restrict__ glist) {
    __shared__ __align__(16) unsigned short As[128 * 32];
    __shared__ __align__(16) unsigned short Bs[128 * 32];
    __shared__ unsigned lds_list[LCAP];
    __shared__ unsigned lds_cnt, lds_base, lds_tot;

    int tid = threadIdx.x;
    if (FUSED && tid == 0) lds_cnt = 0;

    int lane = tid & 63, wv = tid >> 6;
    int wr = wv >> 1, wc = wv & 1;

    // XCD-chunked swizzle (528 = 8*66, bijective), then triangular decode
    int braw = blockIdx.x;
    int b = (braw & 7) * (NBLK / 8) + (braw >> 3);
    int ti = 0;
    while (b >= NT - ti) { b -= NT - ti; ++ti; }
    int tj = ti + b;
    int n0 = ti * 128, m0 = tj * 128;

    f32x4 acc[4][4] = {};
    int lrow = lane >> 2;
    int lchunk = (((lane & 3) ^ (lrow & 3)) * 8);   // pre-swizzled k-offset

    for (int k0 = 0; k0 < KK; k0 += 32) {
#pragma unroll
        for (int h = 0; h < 2; ++h) {
            int s = h * 4 + wv;
            int row = s * 16 + lrow;
            __builtin_amdgcn_global_load_lds((gptr_t)(zb + (size_t)(n0 + row) * KK + k0 + lchunk),
                                             (lptr_t)(As + s * 512), 16, 0, 0);
            __builtin_amdgcn_global_load_lds((gptr_t)(zb + (size_t)(m0 + row) * KK + k0 + lchunk),
                                             (lptr_t)(Bs + s * 512), 16, 0, 0);
        }
        __syncthreads();

        bf16x8 af[4], bfr[4];
        int kk_c = lane >> 4;
        int rsel = lane & 15;
        int kphys = (kk_c ^ (rsel & 3)) * 8;        // swizzled read offset
#pragma unroll
        for (int f = 0; f < 4; ++f) {
            af[f]  = *(bf16x8*)&As[(wr * 64 + f * 16 + rsel) * 32 + kphys];
            bfr[f] = *(bf16x8*)&Bs[(wc * 64 + f * 16 + rsel) * 32 + kphys];
        }
#pragma unroll
        for (int i = 0; i < 4; ++i)
#pragma unroll
            for (int j = 0; j < 4; ++j)
                acc[i][j] = __builtin_amdgcn_mfma_f32_16x16x32_bf16(af[i], bfr[j], acc[i][j], 0, 0, 0);
        __syncthreads();
    }

    int colD = lane & 15, rq = lane >> 4;
    bool mir = (ti != tj);
#pragma unroll
    for (int i = 0; i < 4; ++i)
#pragma unroll
        for (int j = 0; j < 4; ++j) {
            int rbase = n0 + wr * 64 + i * 16 + rq * 4;
            int ccol = m0 + wc * 64 + j * 16 + colD;
            float4 mv;
#pragma unroll
            for (int q = 0; q < 4; ++q) {
                float a = acc[i][j][q] * 0.0625f;
                float sv;
                if (FUSED) {
                    bool flg = fabsf(a - 0.1f) < WIN;
                    sv = flg ? a : (a > 0.1f ? a : 0.0f);
                    if (flg) {
                        unsigned pos = atomicAdd(&lds_cnt, 1u);
                        unsigned ent = (unsigned)(rbase + q) | ((unsigned)ccol << 12) |
                                       (mir ? (1u << 24) : 0u);
                        if (pos < LCAP) lds_list[pos] = ent;
                    }
                } else {
                    sv = a;
                }
                out[(size_t)(rbase + q) * N + ccol] = sv;
                ((float*)&mv)[q] = sv;
            }
            if (mir) *(float4*)&out[(size_t)ccol * N + rbase] = mv;
        }

    if (FUSED) {
        __syncthreads();
        if (tid == 0) {
            unsigned tot = lds_cnt;
            unsigned cnt = tot > LCAP ? LCAP : tot;
            lds_tot = cnt;
            lds_base = atomicAdd(gcnt, cnt);
            if (tot > LCAP) atomicOr(govf, 1u);
        }
        __syncthreads();
        unsigned cnt = lds_tot, base = lds_base;
        for (unsigned e = tid; e < cnt; e += 256) {
            unsigned gi = base + e;
            if (gi < CAP) glist[gi] = lds_list[e];
            else atomicOr(govf, 1u);
        }
    }
}

// ---------------------------------------------------------------------------
// K3: exact f64 recompute of worklist entries (64-lane cooperative).
// ---------------------------------------------------------------------------
__global__ __launch_bounds__(256) void k_fix2(const float* __restrict__ c,
                                              const float* __restrict__ w,
                                              const double* __restrict__ rnorm,
                                              const unsigned* __restrict__ gcnt,
                                              const unsigned* __restrict__ glist,
                                              float* __restrict__ out) {
    __shared__ double w2[D][17];
    for (int e = threadIdx.x; e < P * D; e += 256) {
        int p = e >> 7, d = e & 127;
        double wv = (double)w[p * D + d];
        w2[d][p] = wv * wv;
    }
    __syncthreads();

    unsigned count = *gcnt;
    if (count > CAP) count = CAP;
    int lane = threadIdx.x & 63;
    unsigned gw = (blockIdx.x * 256 + threadIdx.x) >> 6;
    unsigned nw = gridDim.x * 4;
    for (unsigned e = gw; e < count; e += nw) {
        unsigned u = glist[e];
        int n = u & 4095, m = (u >> 12) & 4095;
        int d0 = lane, d1 = lane + 64;
        double pr0 = (double)c[n * D + d0] * (double)c[m * D + d0];
        double pr1 = (double)c[n * D + d1] * (double)c[m * D + d1];
        double t = 0.0;
#pragma unroll
        for (int p = 0; p < P; ++p) {
            double s = pr0 * w2[d0][p] + pr1 * w2[d1][p];
            t += s * (rnorm[p * N + n] * rnorm[p * N + m]);
        }
#pragma unroll
        for (int o = 32; o; o >>= 1) t += __shfl_xor(t, o, 64);
        if (lane == 0) {
            double fin = t * 0.0625;
            float res = (fin > 0.1) ? (float)fin : 0.0f;
            out[(size_t)n * N + m] = res;
            if (u >> 24) out[(size_t)m * N + n] = res;
        }
    }
}

// ---------------------------------------------------------------------------
// K4: overflow guard — full-pass resolve, only if worklist overflowed.
// ---------------------------------------------------------------------------
__global__ __launch_bounds__(256) void k_guard(const float* __restrict__ c,
                                               const float* __restrict__ w,
                                               const double* __restrict__ rnorm,
                                               const unsigned* __restrict__ govf,
                                               float* __restrict__ out) {
    if (*govf == 0) return;
    __shared__ double w2[D][17];
    for (int e = threadIdx.x; e < P * D; e += 256) {
        int p = e >> 7, d = e & 127;
        double wv = (double)w[p * D + d];
        w2[d][p] = wv * wv;
    }
    __syncthreads();
    int lane = threadIdx.x & 63;
    size_t stride = (size_t)gridDim.x * 256;
    for (size_t idx0 = (size_t)blockIdx.x * 256 + threadIdx.x; idx0 < (size_t)N * N;
         idx0 += stride) {
        float a = out[idx0];
        bool flg = fabsf(a - 0.1f) < WIN;
        unsigned long long mb = __ballot(flg);
        while (mb) {
            int src = __ffsll(mb) - 1;
            mb &= mb - 1;
            size_t idx = idx0 - lane + src;
            int n = (int)(idx >> 12), m = (int)(idx & (N - 1));
            int d0 = lane, d1 = lane + 64;
            double pr0 = (double)c[n * D + d0] * (double)c[m * D + d0];
            double pr1 = (double)c[n * D + d1] * (double)c[m * D + d1];
            double t = 0.0;
#pragma unroll
            for (int p = 0; p < P; ++p) {
                double s = pr0 * w2[d0][p] + pr1 * w2[d1][p];
                t += s * (rnorm[p * N + n] * rnorm[p * N + m]);
            }
#pragma unroll
            for (int o = 32; o; o >>= 1) t += __shfl_xor(t, o, 64);
            if (lane == src) {
                double fin = t * 0.0625;
                out[idx] = (fin > 0.1) ? (float)fin : 0.0f;
            }
        }
        if (!flg) out[idx0] = (a > 0.1f) ? a : 0.0f;
    }
}

// ---------------------------------------------------------------------------
// Fallback full-pass mask fix (only if ws too small; proven not taken).
// ---------------------------------------------------------------------------
__global__ __launch_bounds__(256) void k_fix_full(const float* __restrict__ c,
                                                  const float* __restrict__ w,
                                                  const double* __restrict__ rnorm,
                                                  float* __restrict__ out) {
    __shared__ double w2[D][17];
    for (int e = threadIdx.x; e < P * D; e += 256) {
        int p = e >> 7, d = e & 127;
        double wv = (double)w[p * D + d];
        w2[d][p] = wv * wv;
    }
    __syncthreads();
    int tid = threadIdx.x;
    int lane = tid & 63;
    int wvb = tid & ~63;
    size_t base4 = (size_t)blockIdx.x * 256 + tid;
    float4 v = *(float4*)&out[base4 * 4];
    float vv[4] = {v.x, v.y, v.z, v.w};
    bool resolved[4] = {false, false, false, false};
#pragma unroll
    for (int j = 0; j < 4; ++j) {
        bool flag = fabsf(vv[j] - 0.1f) < WIN;
        unsigned long long mb = __ballot(flag);
        while (mb) {
            int src = __ffsll(mb) - 1;
            mb &= mb - 1;
            size_t idx = ((size_t)blockIdx.x * 256 + wvb + src) * 4 + j;
            int n = (int)(idx >> 12), m = (int)(idx & (N - 1));
            int d0 = lane, d1 = lane + 64;
            double pr0 = (double)c[n * D + d0] * (double)c[m * D + d0];
            double pr1 = (double)c[n * D + d1] * (double)c[m * D + d1];
            double t = 0.0;
#pragma unroll
            for (int p = 0; p < P; ++p) {
                double s = pr0 * w2[d0][p] + pr1 * w2[d1][p];
                t += s * (rnorm[p * N + n] * rnorm[p * N + m]);
            }
#pragma unroll
            for (int o = 32; o; o >>= 1) t += __shfl_xor(t, o, 64);
            if (lane == src) {
                double fin = t * 0.0625;
                vv[j] = (fin > 0.1) ? (float)fin : 0.0f;
                resolved[j] = true;
            }
        }
        if (!resolved[j]) vv[j] = (vv[j] > 0.1f) ? vv[j] : 0.0f;
    }
    *(float4*)&out[base4 * 4] = make_float4(vv[0], vv[1], vv[2], vv[3]);
}

// ---------------------------------------------------------------------------
extern "C" void kernel_launch(void* const* d_in, const int* in_sizes, int n_in,
                              void* d_out, int out_size, void* d_ws, size_t ws_size,
                              hipStream_t stream) {
    const float* c = (const float*)d_in[0];
    const float* w = (const float*)d_in[1];
    float* out = (float*)d_out;
    char* ws = (char*)d_ws;

    double* rnorm = (double*)ws;                               // 512 KB
    size_t off = (size_t)P * N * 8;
    unsigned* gcnt = (unsigned*)(ws + off);
    unsigned* govf = gcnt + 1;
    unsigned* glist = (unsigned*)(ws + off + 128);             // 4 MB
    unsigned short* zb = (unsigned short*)(ws + off + 128 + (size_t)CAP * 4);  // 16 MB
    size_t need = off + 128 + (size_t)CAP * 4 + (size_t)N * KK * 2;

    if (ws_size >= need) {
        k_pack<<<N, 256, 0, stream>>>(c, w, rnorm, zb, gcnt, govf, 1);
        k_gemm<true><<<NBLK, 256, 0, stream>>>(zb, out, gcnt, govf, glist);
        k_fix2<<<1024, 256, 0, stream>>>(c, w, rnorm, gcnt, glist, out);
        k_guard<<<1024, 256, 0, stream>>>(c, w, rnorm, govf, out);
    } else {
        unsigned short* zb2 = (unsigned short*)(ws + off);
        k_pack<<<N, 256, 0, stream>>>(c, w, rnorm, zb2, nullptr, nullptr, 0);
        k_gemm<false><<<NBLK, 256, 0, stream>>>(zb2, out, nullptr, nullptr, nullptr);
        k_fix_full<<<(size_t)N * N / 1024, 256, 0, stream>>>(c, w, rnorm, out);
    }
}

// Round 5
// 100.301 us; speedup vs baseline: 2.6915x; 2.6915x over previous
//
#include <hip/hip_runtime.h>
#include <math.h>

#define N 4096
#define D 128
#define P 16
#define KK 2048                    // P*D, single f16 plane
#define NT 32
#define NBLK (NT * (NT + 1) / 2)   // 528 upper-tri blocks
#define LCAP 3072                  // per-block LDS worklist (12 KB)
#define CAP (1u << 20)             // global worklist capacity (4 MB)
#define WIN 1.5e-3f                // > 1.1e-3 rigorous scaled-f16 bound
#define ZSCALE 256.0f              // 2^8, exact
#define OSCALE (1.0f / 16777216.0f * 16.0f)  // 0.0625 * 2^-16 = 2^-20, exact

typedef _Float16 half_t;
typedef __attribute__((ext_vector_type(8))) _Float16 f16x8;
typedef __attribute__((ext_vector_type(4))) float f32x4;
typedef __attribute__((address_space(1))) const unsigned int* gptr_t;
typedef __attribute__((address_space(3))) unsigned int* lptr_t;

// ---------------------------------------------------------------------------
// K1: fused norms (f64, cross-lane reduce) + scaled f16 pack + counter init.
// Block n; thread t: p = t>>4, d0 = (t&15)*8.
// ---------------------------------------------------------------------------
__global__ __launch_bounds__(256) void k_pack(const float* __restrict__ c,
                                              const float* __restrict__ w,
                                              double* __restrict__ rnorm,
                                              half_t* __restrict__ zb,
                                              unsigned* gcnt, unsigned* govf,
                                              int do_init) {
    int n = blockIdx.x, tid = threadIdx.x;
    if (do_init && n == 0 && tid == 0) { *gcnt = 0; *govf = 0; }
    int p = tid >> 4, d0 = (tid & 15) * 8;
    const float* cc = c + (size_t)n * D + d0;
    const float* ww = w + (size_t)p * D + d0;
    float cv[8], wv[8];
    *(float4*)&cv[0] = *(const float4*)&cc[0];
    *(float4*)&cv[4] = *(const float4*)&cc[4];
    *(float4*)&wv[0] = *(const float4*)&ww[0];
    *(float4*)&wv[4] = *(const float4*)&ww[4];
    double s = 0.0;
#pragma unroll
    for (int i = 0; i < 8; ++i) {
        double v = (double)cv[i] * (double)wv[i];
        s += v * v;
    }
#pragma unroll
    for (int o = 1; o < 16; o <<= 1) s += __shfl_xor(s, o, 64);
    double rn = 1.0 / fmax(sqrt(s), 1e-12);
    if ((tid & 15) == 0) rnorm[p * N + n] = rn;
    float rnf = (float)rn;
    f16x8 o8;
#pragma unroll
    for (int i = 0; i < 8; ++i) o8[i] = (half_t)(cv[i] * wv[i] * rnf * ZSCALE);
    *(f16x8*)&zb[(size_t)n * KK + tid * 8] = o8;
}

// ---------------------------------------------------------------------------
// K2: f16 MFMA GEMM out = Z Z^T / 16, fused mask + boundary worklist.
// 128x128 tile, BK=32, 4 waves (2x2 of 64x64). Upper-tri blocks; mirror via
// native float4 store. LDS staging XOR-swizzled via pre-swizzled source.
// ---------------------------------------------------------------------------
template <bool FUSED>
__global__ __launch_bounds__(256, 4) void k_gemm(const half_t* __restrict__ zb,
                                                 float* __restrict__ out,
                                                 unsigned* __restrict__ gcnt,
                                                 unsigned* __restrict__ govf,
                                                 unsigned* __restrict__ glist) {
    __shared__ __align__(16) half_t As[128 * 32];
    __shared__ __align__(16) half_t Bs[128 * 32];
    __shared__ unsigned lds_list[LCAP];
    __shared__ unsigned lds_cnt, lds_base, lds_tot;

    int tid = threadIdx.x;
    if (FUSED && tid == 0) lds_cnt = 0;

    int lane = tid & 63, wv = tid >> 6;
    int wr = wv >> 1, wc = wv & 1;

    // XCD-chunked swizzle (528 = 8*66, bijective), then triangular decode
    int braw = blockIdx.x;
    int b = (braw & 7) * (NBLK / 8) + (braw >> 3);
    int ti = 0;
    while (b >= NT - ti) { b -= NT - ti; ++ti; }
    int tj = ti + b;
    int n0 = ti * 128, m0 = tj * 128;

    f32x4 acc[4][4] = {};
    int lrow = lane >> 2;
    int lchunk = (((lane & 3) ^ (lrow & 3)) * 8);   // pre-swizzled k-offset

    for (int k0 = 0; k0 < KK; k0 += 32) {
#pragma unroll
        for (int h = 0; h < 2; ++h) {
            int s = h * 4 + wv;
            int row = s * 16 + lrow;
            __builtin_amdgcn_global_load_lds((gptr_t)(zb + (size_t)(n0 + row) * KK + k0 + lchunk),
                                             (lptr_t)(As + s * 512), 16, 0, 0);
            __builtin_amdgcn_global_load_lds((gptr_t)(zb + (size_t)(m0 + row) * KK + k0 + lchunk),
                                             (lptr_t)(Bs + s * 512), 16, 0, 0);
        }
        __syncthreads();

        f16x8 af[4], bfr[4];
        int kk_c = lane >> 4;
        int rsel = lane & 15;
        int kphys = (kk_c ^ (rsel & 3)) * 8;        // swizzled read offset
#pragma unroll
        for (int f = 0; f < 4; ++f) {
            af[f]  = *(f16x8*)&As[(wr * 64 + f * 16 + rsel) * 32 + kphys];
            bfr[f] = *(f16x8*)&Bs[(wc * 64 + f * 16 + rsel) * 32 + kphys];
        }
#pragma unroll
        for (int i = 0; i < 4; ++i)
#pragma unroll
            for (int j = 0; j < 4; ++j)
                acc[i][j] = __builtin_amdgcn_mfma_f32_16x16x32_f16(af[i], bfr[j], acc[i][j], 0, 0, 0);
        __syncthreads();
    }

    int colD = lane & 15, rq = lane >> 4;
    bool mir = (ti != tj);
#pragma unroll
    for (int i = 0; i < 4; ++i)
#pragma unroll
        for (int j = 0; j < 4; ++j) {
            int rbase = n0 + wr * 64 + i * 16 + rq * 4;
            int ccol = m0 + wc * 64 + j * 16 + colD;
            float4 mv;
#pragma unroll
            for (int q = 0; q < 4; ++q) {
                float a = acc[i][j][q] * OSCALE;
                float sv;
                if (FUSED) {
                    bool flg = fabsf(a - 0.1f) < WIN;
                    sv = flg ? a : (a > 0.1f ? a : 0.0f);
                    if (flg) {
                        unsigned pos = atomicAdd(&lds_cnt, 1u);
                        unsigned ent = (unsigned)(rbase + q) | ((unsigned)ccol << 12) |
                                       (mir ? (1u << 24) : 0u);
                        if (pos < LCAP) lds_list[pos] = ent;
                    }
                } else {
                    sv = a;
                }
                out[(size_t)(rbase + q) * N + ccol] = sv;
                ((float*)&mv)[q] = sv;
            }
            if (mir) *(float4*)&out[(size_t)ccol * N + rbase] = mv;
        }

    if (FUSED) {
        __syncthreads();
        if (tid == 0) {
            unsigned tot = lds_cnt;
            unsigned cnt = tot > LCAP ? LCAP : tot;
            lds_tot = cnt;
            lds_base = atomicAdd(gcnt, cnt);
            if (tot > LCAP) atomicOr(govf, 1u);
        }
        __syncthreads();
        unsigned cnt = lds_tot, base = lds_base;
        for (unsigned e = tid; e < cnt; e += 256) {
            unsigned gi = base + e;
            if (gi < CAP) glist[gi] = lds_list[e];
            else atomicOr(govf, 1u);
        }
    }
}

// ---------------------------------------------------------------------------
// K3: exact f64 recompute of worklist entries — ONE ENTRY PER LANE.
// 16 independent f64 accumulators (full ILP), float4 gathers of c rows,
// LDS-broadcast w^2 (all lanes read same address each step).
// ---------------------------------------------------------------------------
__global__ __launch_bounds__(256) void k_fix2(const float* __restrict__ c,
                                              const float* __restrict__ w,
                                              const double* __restrict__ rnorm,
                                              const unsigned* __restrict__ gcnt,
                                              const unsigned* __restrict__ glist,
                                              float* __restrict__ out) {
    __shared__ double w2[D * P];   // w2[d*16+p], 16 KB
    for (int e = threadIdx.x; e < P * D; e += 256) {
        int p = e >> 7, d = e & 127;
        double wv = (double)w[p * D + d];
        w2[d * P + p] = wv * wv;
    }
    __syncthreads();

    unsigned count = *gcnt;
    if (count > CAP) count = CAP;
    unsigned stride = gridDim.x * 256;
    for (unsigned e = blockIdx.x * 256 + threadIdx.x; e < count; e += stride) {
        unsigned u = glist[e];
        int n = u & 4095, m = (u >> 12) & 4095;
        const float* cn = c + (size_t)n * D;
        const float* cm = c + (size_t)m * D;
        double acc[P];
#pragma unroll
        for (int p = 0; p < P; ++p) acc[p] = 0.0;
        for (int d0 = 0; d0 < D; d0 += 4) {
            float4 a4 = *(const float4*)&cn[d0];
            float4 b4 = *(const float4*)&cm[d0];
            float av[4] = {a4.x, a4.y, a4.z, a4.w};
            float bv[4] = {b4.x, b4.y, b4.z, b4.w};
#pragma unroll
            for (int q = 0; q < 4; ++q) {
                double pr = (double)av[q] * (double)bv[q];
#pragma unroll
                for (int p = 0; p < P; ++p) acc[p] += pr * w2[(d0 + q) * P + p];
            }
        }
        double t = 0.0;
#pragma unroll
        for (int p = 0; p < P; ++p)
            t += acc[p] * (rnorm[p * N + n] * rnorm[p * N + m]);
        double fin = t * 0.0625;
        float res = (fin > 0.1) ? (float)fin : 0.0f;
        out[(size_t)n * N + m] = res;
        if (u >> 24) out[(size_t)m * N + n] = res;
    }
}

// ---------------------------------------------------------------------------
// K4: overflow guard — full-pass resolve, only if worklist overflowed.
// ---------------------------------------------------------------------------
__global__ __launch_bounds__(256) void k_guard(const float* __restrict__ c,
                                               const float* __restrict__ w,
                                               const double* __restrict__ rnorm,
                                               const unsigned* __restrict__ govf,
                                               float* __restrict__ out) {
    if (*govf == 0) return;
    __shared__ double w2[D * P];
    for (int e = threadIdx.x; e < P * D; e += 256) {
        int p = e >> 7, d = e & 127;
        double wv = (double)w[p * D + d];
        w2[d * P + p] = wv * wv;
    }
    __syncthreads();
    size_t stride = (size_t)gridDim.x * 256;
    for (size_t idx = (size_t)blockIdx.x * 256 + threadIdx.x; idx < (size_t)N * N;
         idx += stride) {
        float a = out[idx];
        if (fabsf(a - 0.1f) >= WIN) {
            out[idx] = (a > 0.1f) ? a : 0.0f;
            continue;
        }
        int n = (int)(idx >> 12), m = (int)(idx & (N - 1));
        const float* cn = c + (size_t)n * D;
        const float* cm = c + (size_t)m * D;
        double acc[P];
#pragma unroll
        for (int p = 0; p < P; ++p) acc[p] = 0.0;
        for (int d0 = 0; d0 < D; d0 += 4) {
            float4 a4 = *(const float4*)&cn[d0];
            float4 b4 = *(const float4*)&cm[d0];
            float av[4] = {a4.x, a4.y, a4.z, a4.w};
            float bv[4] = {b4.x, b4.y, b4.z, b4.w};
#pragma unroll
            for (int q = 0; q < 4; ++q) {
                double pr = (double)av[q] * (double)bv[q];
#pragma unroll
                for (int p = 0; p < P; ++p) acc[p] += pr * w2[(d0 + q) * P + p];
            }
        }
        double t = 0.0;
#pragma unroll
        for (int p = 0; p < P; ++p)
            t += acc[p] * (rnorm[p * N + n] * rnorm[p * N + m]);
        double fin = t * 0.0625;
        out[idx] = (fin > 0.1) ? (float)fin : 0.0f;
    }
}

// ---------------------------------------------------------------------------
// Fallback full-pass mask fix (only if ws too small; proven not taken).
// ---------------------------------------------------------------------------
__global__ __launch_bounds__(256) void k_fix_full(const float* __restrict__ c,
                                                  const float* __restrict__ w,
                                                  const double* __restrict__ rnorm,
                                                  float* __restrict__ out) {
    __shared__ double w2[D * P];
    for (int e = threadIdx.x; e < P * D; e += 256) {
        int p = e >> 7, d = e & 127;
        double wv = (double)w[p * D + d];
        w2[d * P + p] = wv * wv;
    }
    __syncthreads();
    size_t stride = (size_t)gridDim.x * 256;
    for (size_t idx = (size_t)blockIdx.x * 256 + threadIdx.x; idx < (size_t)N * N;
         idx += stride) {
        float a = out[idx];
        if (fabsf(a - 0.1f) >= WIN) {
            out[idx] = (a > 0.1f) ? a : 0.0f;
            continue;
        }
        int n = (int)(idx >> 12), m = (int)(idx & (N - 1));
        const float* cn = c + (size_t)n * D;
        const float* cm = c + (size_t)m * D;
        double acc[P];
#pragma unroll
        for (int p = 0; p < P; ++p) acc[p] = 0.0;
        for (int d0 = 0; d0 < D; d0 += 4) {
            float4 a4 = *(const float4*)&cn[d0];
            float4 b4 = *(const float4*)&cm[d0];
            float av[4] = {a4.x, a4.y, a4.z, a4.w};
            float bv[4] = {b4.x, b4.y, b4.z, b4.w};
#pragma unroll
            for (int q = 0; q < 4; ++q) {
                double pr = (double)av[q] * (double)bv[q];
#pragma unroll
                for (int p = 0; p < P; ++p) acc[p] += pr * w2[(d0 + q) * P + p];
            }
        }
        double t = 0.0;
#pragma unroll
        for (int p = 0; p < P; ++p)
            t += acc[p] * (rnorm[p * N + n] * rnorm[p * N + m]);
        double fin = t * 0.0625;
        out[idx] = (fin > 0.1) ? (float)fin : 0.0f;
    }
}

// ---------------------------------------------------------------------------
extern "C" void kernel_launch(void* const* d_in, const int* in_sizes, int n_in,
                              void* d_out, int out_size, void* d_ws, size_t ws_size,
                              hipStream_t stream) {
    const float* c = (const float*)d_in[0];
    const float* w = (const float*)d_in[1];
    float* out = (float*)d_out;
    char* ws = (char*)d_ws;

    double* rnorm = (double*)ws;                               // 512 KB
    size_t off = (size_t)P * N * 8;
    unsigned* gcnt = (unsigned*)(ws + off);
    unsigned* govf = gcnt + 1;
    unsigned* glist = (unsigned*)(ws + off + 128);             // 4 MB
    half_t* zb = (half_t*)(ws + off + 128 + (size_t)CAP * 4);  // 16 MB
    size_t need = off + 128 + (size_t)CAP * 4 + (size_t)N * KK * 2;

    if (ws_size >= need) {
        k_pack<<<N, 256, 0, stream>>>(c, w, rnorm, zb, gcnt, govf, 1);
        k_gemm<true><<<NBLK, 256, 0, stream>>>(zb, out, gcnt, govf, glist);
        k_fix2<<<1024, 256, 0, stream>>>(c, w, rnorm, gcnt, glist, out);
        k_guard<<<1024, 256, 0, stream>>>(c, w, rnorm, govf, out);
    } else {
        half_t* zb2 = (half_t*)(ws + off);
        k_pack<<<N, 256, 0, stream>>>(c, w, rnorm, zb2, nullptr, nullptr, 0);
        k_gemm<false><<<NBLK, 256, 0, stream>>>(zb2, out, nullptr, nullptr, nullptr);
        k_fix_full<<<4096, 256, 0, stream>>>(c, w, rnorm, out);
    }
}